// Round 3
// baseline (600.615 us; speedup 1.0000x reference)
//
#include <hip/hip_runtime.h>
#include <math.h>

// Problem constants (from reference)
constexpr int NP = 20;   // N_PRED
constexpr int NL = 12;   // L
// LAMBDA_POS = LAMBDA_RAD = LAMBDA_UNPAIR = 0.5, EPS = 1e-6

// Fast natural log: v_log_f32 (log2, ~1 ulp) * ln(2). Used ONLY for loss
// values (never the argmin ordering), where the 0.0156 absmax tolerance
// gives huge slack; error ~2e-6 absolute.
__device__ __forceinline__ float fast_log(float x) {
    return __builtin_amdgcn_logf(x) * 0.69314718055994530942f;
}

// ROUND-3 STRUCTURE (latency fix): p-outer / l-inner loop interchange.
//  - round-2 counters: VALUBusy 48%, HBM 27%, occupancy ~40% -> latency-
//    bound. The 12 label loads were issued at the top of each l-iteration
//    and consumed immediately; with L1 (32KB/CU) thrashed by streaming
//    waves, each was an exposed L2/HBM-latency stall.
//  - now: all 12 labels preloaded in ONE pipelined miss window (3 lines);
//    preds stream 1 float4/iteration with depth-1 prefetch, covered by
//    ~170 VALU ops of 12 independent (great ILP) label argmin chains.
//  - rule #20: every state-array access is in a fully-unrolled l-loop
//    (compile-time index). Runtime p only forms addresses / (1u<<p).
__global__ __launch_bounds__(256, 4) void myloss_kernel(
    const float4* __restrict__ pred,    // (B, 20, 4) as float4
    const float4* __restrict__ label,   // (B, 12, 4) as float4
    float* __restrict__ out,            // (B,)
    int B)
{
    int b = blockIdx.x * blockDim.x + threadIdx.x;
    if (b >= B) return;

    const float4* p4 = pred  + (size_t)b * NP;
    const float4* l4 = label + (size_t)b * NL;

    // Preload ALL 12 labels up front (only x,y,r live; .w unused by ref).
    float lx[NL], ly[NL], lr[NL];
#pragma unroll
    for (int l = 0; l < NL; ++l) {
        float4 v = l4[l];
        lx[l] = v.x; ly[l] = v.y; lr[l] = v.z;
    }

    // Per-label argmin state: min1, min2 (guard), winner q/r/bit.
    float m1[NL], m2[NL], wq[NL], wr[NL];
    unsigned wb[NL];
#pragma unroll
    for (int l = 0; l < NL; ++l) {
        m1[l] = INFINITY; m2[l] = INFINITY;
        wq[l] = 0.0f; wr[l] = 0.0f; wb[l] = 0u;
    }

    float lu_all = 0.0f;   // unpair term summed over ALL preds

    // FAST-PATH ARGMIN with exactness guard (as verified in round 2):
    //   s_fast = raw v_sqrt_f32 + fma-contracted d2; |s_fast-s_exact|
    //   <= ~5e-7. Sequential strict-< first-wins over p matches
    //   np.argmin ordering exactly; a flip vs exact values requires
    //   min2-min1 < TAU=4e-6, which triggers the exact fallback.
    float4 pv = p4[0];
#pragma unroll 1
    for (int p = 0; p < NP; ++p) {
        float4 pnext = p4[(p < NP - 1) ? (p + 1) : (NP - 1)]; // prefetch
        unsigned pbit = 1u << p;

        // unpair term for every pred; matched ones subtracted later with
        // bitwise-identical recompute (same inputs, same ops).
        lu_all += (-fast_log(1.0f - pv.w + 1e-6f) + 0.5f * pv.z) * 0.5f;

#pragma unroll
        for (int l = 0; l < NL; ++l) {
            float dx = lx[l] - pv.x;
            float dy = ly[l] - pv.y;
            float d2 = __builtin_fmaf(dy, dy, dx * dx);   // contraction OK (guarded)
            float dist = __builtin_amdgcn_sqrtf(d2);      // raw v_sqrt_f32
            float s = dist + fabsf(lr[l] - pv.z);
            // second-min BEFORE first-min update (uses old m1)
            m2[l] = fminf(m2[l], fmaxf(m1[l], s));
            bool lt = s < m1[l];
            m1[l] = lt ? s : m1[l];
            wq[l] = lt ? pv.w : wq[l];
            wr[l] = lt ? pv.z : wr[l];
            wb[l] = lt ? pbit : wb[l];
        }
        pv = pnext;
    }

    // Guard check + rare exact fallback (numpy-identical argmin:
    // contract-off, correctly-rounded sqrtf, strict-< first-wins).
    // Reloads pred from GLOBAL (runtime p -> VMEM load, never scratch).
#pragma unroll
    for (int l = 0; l < NL; ++l) {
        if (m2[l] - m1[l] < 4e-6f) {
            float sm = INFINITY, qq = 0.0f, rr = 0.0f;
            unsigned bb = 0u;
#pragma unroll 1
            for (int p = 0; p < NP; ++p) {
                float4 v = p4[p];
                float s;
                {
#pragma clang fp contract(off)
                    float dx = lx[l] - v.x;
                    float dy = ly[l] - v.y;
                    float d2 = dx * dx + dy * dy;
                    s = sqrtf(d2) + fabsf(lr[l] - v.z);
                }
                bool ltp = s < sm;
                sm = ltp ? s : sm;
                qq = ltp ? v.w : qq;
                rr = ltp ? v.z : rr;
                bb = ltp ? (1u << p) : bb;
            }
            m1[l] = sm; wq[l] = qq; wr[l] = rr; wb[l] = bb;
        }
    }

    // Epilogue: pair loss + dedup'd subtraction of matched unpair terms.
    float lp = 0.0f;
    unsigned seen = 0u;
#pragma unroll
    for (int l = 0; l < NL; ++l) {
        lp += 0.5f * m1[l] - fast_log(wq[l] + 1e-6f);
        float t = (-fast_log(1.0f - wq[l] + 1e-6f) + 0.5f * wr[l]) * 0.5f;
        lu_all -= (wb[l] & seen) ? 0.0f : t;   // subtract once per distinct pred
        seen |= wb[l];
    }

    out[b] = lp * (1.0f / 12.0f) + lu_all * 0.125f;  // /L + /(N_PRED-L)
}

extern "C" void kernel_launch(void* const* d_in, const int* in_sizes, int n_in,
                              void* d_out, int out_size, void* d_ws, size_t ws_size,
                              hipStream_t stream) {
    const float4* pred  = (const float4*)d_in[0];
    const float4* label = (const float4*)d_in[1];
    float* out = (float*)d_out;
    int B = out_size;
    int threads = 256;
    int blocks = (B + threads - 1) / threads;
    hipLaunchKernelGGL(myloss_kernel, dim3(blocks), dim3(threads), 0, stream,
                       pred, label, out, B);
}

// Round 4
// 548.403 us; speedup vs baseline: 1.0952x; 1.0952x over previous
//
#include <hip/hip_runtime.h>
#include <math.h>

// Problem constants (from reference)
constexpr int NP = 20;   // N_PRED
constexpr int NL = 12;   // L
// LAMBDA_POS = LAMBDA_RAD = LAMBDA_UNPAIR = 0.5, EPS = 1e-6

// Fast natural log: v_log_f32 (log2, ~1 ulp) * ln(2). Used ONLY for loss
// values (never the argmin ordering), where the 0.0156 absmax tolerance
// gives huge slack; error ~2e-6 absolute.
__device__ __forceinline__ float fast_log(float x) {
    return __builtin_amdgcn_logf(x) * 0.69314718055994530942f;
}

// ROUND-4 STRUCTURE (latency fix, take 2): batched software pipeline.
//  - rounds 2/3 were latency-bound (VALUBusy ~50%, HBM 27%): loads were
//    issued one-at-a-time with ~340 cyc of cover vs ~900 cyc HBM latency.
//  - now: preds stream in BATCHES OF 5 float4s, double-buffered. Batch
//    t+1's 5 loads are issued BEFORE computing batch t (60 pair-evals
//    ~1700 cyc of cover). Labels (3 lines) + batch 0 fill one pipelined
//    prologue miss window.
//  - __launch_bounds__(256,3): VGPR cap ~170 for ~146 live (36 label +
//    60 state + 40 double-batch + misc). Measured occupancy was ~40%
//    anyway, so the 3-waves/SIMD bucket costs nothing.
//  - rule #20: state arrays (m1,m2,wq,wr,wb, lx,ly,lr) are ONLY indexed
//    by compile-time constants (unrolled l-loops, lambda-expanded pred
//    slots). Runtime p only forms addresses and (1u<<p).
__global__ __launch_bounds__(256, 3) void myloss_kernel(
    const float4* __restrict__ pred,    // (B, 20, 4) as float4
    const float4* __restrict__ label,   // (B, 12, 4) as float4
    float* __restrict__ out,            // (B,)
    int B)
{
    int b = blockIdx.x * blockDim.x + threadIdx.x;
    if (b >= B) return;

    const float4* p4 = pred  + (size_t)b * NP;
    const float4* l4 = label + (size_t)b * NL;

    // ---- prologue: one pipelined miss window (labels + pred batch 0) ----
    float lx[NL], ly[NL], lr[NL];
#pragma unroll
    for (int l = 0; l < NL; ++l) {
        float4 v = l4[l];
        lx[l] = v.x; ly[l] = v.y; lr[l] = v.z;
    }
    float4 c0 = p4[0], c1 = p4[1], c2 = p4[2], c3 = p4[3], c4 = p4[4];

    // Per-label argmin state: min1, min2 (exactness guard), winner q/r/bit.
    float m1[NL], m2[NL], wq[NL], wr[NL];
    unsigned wb[NL];
#pragma unroll
    for (int l = 0; l < NL; ++l) {
        m1[l] = INFINITY; m2[l] = INFINITY;
        wq[l] = 0.0f; wr[l] = 0.0f; wb[l] = 0u;
    }

    float lu_all = 0.0f;   // unpair term summed over ALL preds

    // FAST-PATH eval (verified rounds 2-3): raw v_sqrt_f32 + fma-contracted
    // d2; |s_fast - s_exact| <= ~5e-7. Strict-< first-wins over p matches
    // np.argmin; any min2-min1 < TAU=4e-6 triggers the exact fallback.
    auto evalPred = [&](float4 pv, unsigned pbit) {
        lu_all += (-fast_log(1.0f - pv.w + 1e-6f) + 0.5f * pv.z) * 0.5f;
#pragma unroll
        for (int l = 0; l < NL; ++l) {
            float dx = lx[l] - pv.x;
            float dy = ly[l] - pv.y;
            float d2 = __builtin_fmaf(dy, dy, dx * dx);   // contraction OK (guarded)
            float dist = __builtin_amdgcn_sqrtf(d2);      // raw v_sqrt_f32
            float s = dist + fabsf(lr[l] - pv.z);
            // second-min BEFORE first-min update (uses old m1)
            m2[l] = fminf(m2[l], fmaxf(m1[l], s));
            bool lt = s < m1[l];
            m1[l] = lt ? s : m1[l];
            wq[l] = lt ? pv.w : wq[l];
            wr[l] = lt ? pv.z : wr[l];
            wb[l] = lt ? pbit : wb[l];
        }
    };

    // ---- main loop: 4 batches of 5, double-buffered ----
#pragma unroll 1
    for (int t = 0; t < 4; ++t) {
        // issue next batch's loads first (clamped on last iter: 2 L1-hot
        // lines, keeps control flow flat)
        int nb = (t < 3) ? (t * 5 + 5) : 0;
        float4 n0 = p4[nb + 0];
        float4 n1 = p4[nb + 1];
        float4 n2 = p4[nb + 2];
        float4 n3 = p4[nb + 3];
        float4 n4 = p4[nb + 4];

        unsigned base_bit = 1u << (t * 5);
        evalPred(c0, base_bit);
        evalPred(c1, base_bit << 1);
        evalPred(c2, base_bit << 2);
        evalPred(c3, base_bit << 3);
        evalPred(c4, base_bit << 4);

        c0 = n0; c1 = n1; c2 = n2; c3 = n3; c4 = n4;
    }

    // Guard check + rare exact fallback (numpy-identical argmin:
    // contract-off, correctly-rounded sqrtf, strict-< first-wins).
    // Reloads pred from GLOBAL (runtime p -> VMEM load, never scratch).
#pragma unroll
    for (int l = 0; l < NL; ++l) {
        if (m2[l] - m1[l] < 4e-6f) {
            float sm = INFINITY, qq = 0.0f, rr = 0.0f;
            unsigned bb = 0u;
#pragma unroll 1
            for (int p = 0; p < NP; ++p) {
                float4 v = p4[p];
                float s;
                {
#pragma clang fp contract(off)
                    float dx = lx[l] - v.x;
                    float dy = ly[l] - v.y;
                    float d2 = dx * dx + dy * dy;
                    s = sqrtf(d2) + fabsf(lr[l] - v.z);
                }
                bool ltp = s < sm;
                sm = ltp ? s : sm;
                qq = ltp ? v.w : qq;
                rr = ltp ? v.z : rr;
                bb = ltp ? (1u << p) : bb;
            }
            m1[l] = sm; wq[l] = qq; wr[l] = rr; wb[l] = bb;
        }
    }

    // Epilogue: pair loss + dedup'd subtraction of matched unpair terms
    // (bitwise-identical recompute of the matched preds' terms).
    float lp = 0.0f;
    unsigned seen = 0u;
#pragma unroll
    for (int l = 0; l < NL; ++l) {
        lp += 0.5f * m1[l] - fast_log(wq[l] + 1e-6f);
        float t = (-fast_log(1.0f - wq[l] + 1e-6f) + 0.5f * wr[l]) * 0.5f;
        lu_all -= (wb[l] & seen) ? 0.0f : t;   // subtract once per distinct pred
        seen |= wb[l];
    }

    out[b] = lp * (1.0f / 12.0f) + lu_all * 0.125f;  // /L + /(N_PRED-L)
}

extern "C" void kernel_launch(void* const* d_in, const int* in_sizes, int n_in,
                              void* d_out, int out_size, void* d_ws, size_t ws_size,
                              hipStream_t stream) {
    const float4* pred  = (const float4*)d_in[0];
    const float4* label = (const float4*)d_in[1];
    float* out = (float*)d_out;
    int B = out_size;
    int threads = 256;
    int blocks = (B + threads - 1) / threads;
    hipLaunchKernelGGL(myloss_kernel, dim3(blocks), dim3(threads), 0, stream,
                       pred, label, out, B);
}